// Round 2
// baseline (647.251 us; speedup 1.0000x reference)
//
#include <hip/hip_runtime.h>
#include <hip/hip_bf16.h>

// ParallelFreqAwareEmbeddingBagTablewise: mean-pooled embedding bags.
// indices: [N] int32 global row ids (N = T*B*L)
// offsets: [num_bags] int32 bag starts (num_bags = T*B, bags contiguous, sorted)
// weight:  [T*V, D] float32 (D=64)
// out:     [B, T*D] float32 ; bag i = (t, b) with t = i / B, b = i % B
//          writes out[b*T*D + t*D + d]

constexpr int D = 64;      // embedding dim (16 lanes * float4)
constexpr int TD = 512;    // T * D

__global__ __launch_bounds__(256)
void embag_mean_kernel(const int* __restrict__ indices,
                       const int* __restrict__ offsets,
                       const float* __restrict__ weight,
                       float* __restrict__ out,
                       int num_bags, int N, int B) {
    const int wave = (blockIdx.x * blockDim.x + threadIdx.x) >> 6;
    const int lane = threadIdx.x & 63;
    if (wave >= num_bags) return;

    const int start = offsets[wave];
    const int end   = (wave + 1 < num_bags) ? offsets[wave + 1] : N;
    const int count = end - start;

    const int sub = lane >> 4;   // 0..3: which row of a 4-row group this lane helps load
    const int l4  = lane & 15;   // covers dims [l4*4, l4*4+4)

    float4 acc = make_float4(0.f, 0.f, 0.f, 0.f);

    if (count == 20) {
        // Fast path (all bags in this workload): fully unrolled, 5 independent
        // 256 B row loads in flight per quarter-wave (5 KB/wave outstanding).
        const int jb = start + sub;
        const int r0 = indices[jb];
        const int r1 = indices[jb + 4];
        const int r2 = indices[jb + 8];
        const int r3 = indices[jb + 12];
        const int r4 = indices[jb + 16];
        const float4 v0 = reinterpret_cast<const float4*>(weight + (size_t)r0 * D)[l4];
        const float4 v1 = reinterpret_cast<const float4*>(weight + (size_t)r1 * D)[l4];
        const float4 v2 = reinterpret_cast<const float4*>(weight + (size_t)r2 * D)[l4];
        const float4 v3 = reinterpret_cast<const float4*>(weight + (size_t)r3 * D)[l4];
        const float4 v4 = reinterpret_cast<const float4*>(weight + (size_t)r4 * D)[l4];
        acc.x = v0.x + v1.x + v2.x + v3.x + v4.x;
        acc.y = v0.y + v1.y + v2.y + v3.y + v4.y;
        acc.z = v0.z + v1.z + v2.z + v3.z + v4.z;
        acc.w = v0.w + v1.w + v2.w + v3.w + v4.w;
    } else {
        // General path: any bag length (including 0).
        for (int j = start + sub; j < end; j += 4) {
            const int row = indices[j];
            const float4 v = reinterpret_cast<const float4*>(weight + (size_t)row * D)[l4];
            acc.x += v.x; acc.y += v.y; acc.z += v.z; acc.w += v.w;
        }
    }

    // Reduce the 4 quarter-wave partials (lanes l4, l4+16, l4+32, l4+48).
    acc.x += __shfl_xor(acc.x, 16); acc.y += __shfl_xor(acc.y, 16);
    acc.z += __shfl_xor(acc.z, 16); acc.w += __shfl_xor(acc.w, 16);
    acc.x += __shfl_xor(acc.x, 32); acc.y += __shfl_xor(acc.y, 32);
    acc.z += __shfl_xor(acc.z, 32); acc.w += __shfl_xor(acc.w, 32);

    if (sub == 0) {
        const float inv = 1.0f / fmaxf((float)count, 1.0f);
        const int t = wave / B;         // bags ordered (table, batch)
        const int b = wave - t * B;
        float4 r;
        r.x = acc.x * inv; r.y = acc.y * inv; r.z = acc.z * inv; r.w = acc.w * inv;
        float4* dst = reinterpret_cast<float4*>(out + (size_t)b * TD + t * D);
        dst[l4] = r;                    // 16 lanes * 16 B = full 256 B output row
    }
}

extern "C" void kernel_launch(void* const* d_in, const int* in_sizes, int n_in,
                              void* d_out, int out_size, void* d_ws, size_t ws_size,
                              hipStream_t stream) {
    const int*   indices = (const int*)d_in[0];
    const int*   offsets = (const int*)d_in[1];
    const float* weight  = (const float*)d_in[2];
    float*       out     = (float*)d_out;

    const int N        = in_sizes[0];        // T*B*L
    const int num_bags = in_sizes[1];        // T*B
    const int B        = out_size / TD;      // batch size (out is [B, T*D])

    // One 64-lane wave per bag; 4 waves per 256-thread block.
    const int waves_per_block = 256 / 64;
    const int grid = (num_bags + waves_per_block - 1) / waves_per_block;

    embag_mean_kernel<<<grid, 256, 0, stream>>>(indices, offsets, weight, out,
                                                num_bags, N, B);
}

// Round 4
// 645.304 us; speedup vs baseline: 1.0030x; 1.0030x over previous
//
#include <hip/hip_runtime.h>
#include <hip/hip_bf16.h>

// ParallelFreqAwareEmbeddingBagTablewise: mean-pooled embedding bags.
// indices: [N] int32 global row ids (N = T*B*L)
// offsets: [num_bags] int32 bag starts (num_bags = T*B, bags contiguous, sorted)
// weight:  [T*V, D] float32 (D=64)
// out:     [B, T*D] float32 ; bag i = (t, b) with t = i / B, b = i % B
//
// Layout: one 64-lane wave per bag; lane d owns output dim d.
// The 20 bag indices are broadcast to SGPRs via readlane, so each row read is
// a single scalar-based global_load_dword: 64 lanes x 4 B = one 256 B row,
// fully coalesced, ONE page per instruction (vs 4 rows/instr previously).
// All 20 row loads are independent -> 20 outstanding loads per wave.

constexpr int D = 64;      // embedding dim (one dword per lane)
constexpr int TD = 512;    // T * D

__global__ __launch_bounds__(256)
void embag_mean_kernel(const int* __restrict__ indices,
                       const int* __restrict__ offsets,
                       const float* __restrict__ weight,
                       float* __restrict__ out,
                       int num_bags, int N, int B) {
    const int wave = (blockIdx.x * blockDim.x + threadIdx.x) >> 6;
    const int lane = threadIdx.x & 63;
    if (wave >= num_bags) return;

    const int start = offsets[wave];
    const int end   = (wave + 1 < num_bags) ? offsets[wave + 1] : N;
    const int count = end - start;

    // Output address (hoisted; bags ordered (table, batch)).
    const int t = wave / B;
    const int b = wave - t * B;
    float* const dst = out + (size_t)b * TD + t * D + lane;

    float acc = 0.0f;

    if (count == 20) {
        // Fast path (every bag in this workload has exactly L=20 ids).
        // Lanes 0..19 fetch the bag's indices; others read a harmless dup.
        const int myidx = indices[start + (lane < 20 ? lane : 0)];
        #pragma unroll
        for (int k = 0; k < 20; ++k) {
            const int row = __builtin_amdgcn_readlane(myidx, k);  // SGPR row id
            acc += weight[(size_t)row * D + lane];                // 256 B coalesced
        }
        acc *= (1.0f / 20.0f);
    } else {
        // General path: any bag length (including 0).
        for (int j = start; j < end; ++j) {
            const int row = indices[j];      // uniform across wave -> scalar load
            acc += weight[(size_t)row * D + lane];
        }
        acc *= 1.0f / fmaxf((float)count, 1.0f);
    }

    // Streaming 33 MB output: nontemporal store keeps L3 for the gather table.
    __builtin_nontemporal_store(acc, dst);
}

extern "C" void kernel_launch(void* const* d_in, const int* in_sizes, int n_in,
                              void* d_out, int out_size, void* d_ws, size_t ws_size,
                              hipStream_t stream) {
    const int*   indices = (const int*)d_in[0];
    const int*   offsets = (const int*)d_in[1];
    const float* weight  = (const float*)d_in[2];
    float*       out     = (float*)d_out;

    const int N        = in_sizes[0];        // T*B*L
    const int num_bags = in_sizes[1];        // T*B
    const int B        = out_size / TD;      // batch size (out is [B, T*D])

    // One 64-lane wave per bag; 4 waves per 256-thread block.
    const int waves_per_block = 256 / 64;
    const int grid = (num_bags + waves_per_block - 1) / waves_per_block;

    embag_mean_kernel<<<grid, 256, 0, stream>>>(indices, offsets, weight, out,
                                                num_bags, N, B);
}